// Round 3
// baseline (553.451 us; speedup 1.0000x reference)
//
#include <hip/hip_runtime.h>

// Problem constants: x (16, 256, 128, 128) fp32; W1 (128,256); b1 (128);
// W2 (256,128); b2 (256). Output = selected (16,128,128,128) ++ remaining
// (16,128,128,128), a channel permutation of x.
#define NB 16
#define C  256
#define CH 128
#define HW 16384              // 128*128 floats per plane
#define PLANES (NB * C)       // 4096

// native clang vector type — accepted by __builtin_nontemporal_store
typedef float vfloat4 __attribute__((ext_vector_type(4)));

// ---------------- kernel 1: per-(n,c) spatial mean -------------------------
// Reads x planes 0..4095 ascending; leaves the TAIL of x resident in the
// 256 MB L3 for the gather pass (which walks backward).
__global__ __launch_bounds__(256) void mean_kernel(const float* __restrict__ x,
                                                   float* __restrict__ z) {
    const int plane = blockIdx.x;                 // 0..4095
    const vfloat4* xp = (const vfloat4*)(x + (size_t)plane * HW);
    const int t = threadIdx.x;
    float s = 0.0f;
#pragma unroll
    for (int i = 0; i < 16; ++i) {                // 4096 float4 / 256 threads
        vfloat4 v = xp[t + i * 256];
        s += (v.x + v.y) + (v.z + v.w);
    }
    // wave64 shuffle reduction
#pragma unroll
    for (int off = 32; off > 0; off >>= 1) s += __shfl_down(s, off, 64);
    __shared__ float wsum[4];
    const int lane = t & 63, wave = t >> 6;
    if (lane == 0) wsum[wave] = s;
    __syncthreads();
    if (t == 0) {
        float tot = (wsum[0] + wsum[1]) + (wsum[2] + wsum[3]);
        z[plane] = tot * (1.0f / (float)HW);
    }
}

// ---------------- kernel 2: fused MLP + rank + plane gather ----------------
// One block per OUTPUT plane, traversed 4095 -> 0 (reverse of mean's read
// order, so first reads hit the L3-resident tail of x). Each block
// redundantly recomputes its image's 256 scores + stable descending ranks
// (~1 us of VALU, hidden under other blocks' streaming; weights are
// L2-resident), finds the source channel whose rank equals its output
// position, then streams the 64 KB plane with non-temporal stores.
__global__ __launch_bounds__(256) void mlp_gather_kernel(
        const float* __restrict__ x,
        const float* __restrict__ z,
        const float* __restrict__ W1, const float* __restrict__ b1,
        const float* __restrict__ W2, const float* __restrict__ b2,
        float* __restrict__ out) {
    const int b = (PLANES - 1) - blockIdx.x;   // 4095..0 = output plane (n, p)
    const int n = b >> 8;
    const int p = b & 255;
    const int t = threadIdx.x;                 // 0..255

    __shared__ float zs[C];
    __shared__ float hs[CH];
    __shared__ float sc[C];
    __shared__ int   srcCh;

    zs[t] = z[n * C + t];
    __syncthreads();
    if (t < CH) {
        float acc = b1[t];
        const float* w = W1 + t * C;
        for (int k = 0; k < C; ++k) acc = fmaf(zs[k], w[k], acc);
        hs[t] = fmaxf(acc, 0.0f);
    }
    __syncthreads();
    {
        float acc = b2[t];
        const float* w = W2 + t * CH;
        for (int k = 0; k < CH; ++k) acc = fmaf(hs[k], w[k], acc);
        sc[t] = acc;                // logit; sort order == sigmoid order
    }
    __syncthreads();
    {
        const float mysc = sc[t];
        int rank = 0;
        for (int j = 0; j < C; ++j) {
            float o = sc[j];
            // descending, stable: j precedes t if o > mysc, or tie & j < t
            rank += (o > mysc) || (o == mysc && j < t);
        }
        if (rank == p) srcCh = t;   // exactly one thread matches
    }
    __syncthreads();

    const int src = srcCh;
    const vfloat4* sp = (const vfloat4*)(x + ((size_t)n * C + src) * HW);
    // selected planes first (NB*CH of them), then remaining planes
    const size_t dstPlane = (p < CH)
        ? ((size_t)n * CH + p)
        : ((size_t)NB * CH + (size_t)n * CH + (p - CH));
    vfloat4* dp = (vfloat4*)(out + dstPlane * HW);
#pragma unroll
    for (int i = 0; i < 16; ++i) {
        vfloat4 v = sp[t + i * 256];
        __builtin_nontemporal_store(v, dp + t + i * 256);
    }
}

extern "C" void kernel_launch(void* const* d_in, const int* in_sizes, int n_in,
                              void* d_out, int out_size, void* d_ws, size_t ws_size,
                              hipStream_t stream) {
    const float* x  = (const float*)d_in[0];
    const float* W1 = (const float*)d_in[1];
    const float* b1 = (const float*)d_in[2];
    const float* W2 = (const float*)d_in[3];
    const float* b2 = (const float*)d_in[4];
    float* out = (float*)d_out;

    float* z = (float*)d_ws;                                   // 4096 floats

    mean_kernel<<<PLANES, 256, 0, stream>>>(x, z);
    mlp_gather_kernel<<<PLANES, 256, 0, stream>>>(x, z, W1, b1, W2, b2, out);
}

// Round 4
// 498.096 us; speedup vs baseline: 1.1111x; 1.1111x over previous
//
#include <hip/hip_runtime.h>

// Problem constants: x (16, 256, 128, 128) fp32; W1 (128,256); b1 (128);
// W2 (256,128); b2 (256). Output = selected (16,128,128,128) ++ remaining
// (16,128,128,128), a channel permutation of x.
#define NB 16
#define C  256
#define CH 128
#define HW 16384              // 128*128 floats per plane
#define PLANES (NB * C)       // 4096

// native clang vector type — accepted by __builtin_nontemporal_store
typedef float vfloat4 __attribute__((ext_vector_type(4)));

// ---------------- kernel 1: per-(n,c) spatial mean -------------------------
// Reads x planes 0..4095 ascending; leaves the TAIL of x resident in the
// 256 MB L3 for the gather pass (which walks backward).
__global__ __launch_bounds__(256) void mean_kernel(const float* __restrict__ x,
                                                   float* __restrict__ z) {
    const int plane = blockIdx.x;                 // 0..4095
    const vfloat4* xp = (const vfloat4*)(x + (size_t)plane * HW);
    const int t = threadIdx.x;
    float s = 0.0f;
#pragma unroll
    for (int i = 0; i < 16; ++i) {                // 4096 float4 / 256 threads
        vfloat4 v = xp[t + i * 256];
        s += (v.x + v.y) + (v.z + v.w);
    }
    // wave64 shuffle reduction
#pragma unroll
    for (int off = 32; off > 0; off >>= 1) s += __shfl_down(s, off, 64);
    __shared__ float wsum[4];
    const int lane = t & 63, wave = t >> 6;
    if (lane == 0) wsum[wave] = s;
    __syncthreads();
    if (t == 0) {
        float tot = (wsum[0] + wsum[1]) + (wsum[2] + wsum[3]);
        z[plane] = tot * (1.0f / (float)HW);
    }
}

// ---------------- kernel 2: MLP + stable descending rank -------------------
// One block per batch image (16 blocks, ~5 us). Sort key = pre-sigmoid
// logits (sigmoid is monotonic, ordering identical, numerically safer).
__global__ __launch_bounds__(256) void mlp_sort_kernel(
        const float* __restrict__ z,
        const float* __restrict__ W1, const float* __restrict__ b1,
        const float* __restrict__ W2, const float* __restrict__ b2,
        int* __restrict__ perm) {
    const int n = blockIdx.x;       // 0..15
    const int t = threadIdx.x;      // 0..255
    __shared__ float zs[C];
    __shared__ float hs[CH];
    __shared__ float sc[C];
    zs[t] = z[n * C + t];
    __syncthreads();
    if (t < CH) {
        float acc = b1[t];
        const float* w = W1 + t * C;
        for (int k = 0; k < C; ++k) acc = fmaf(zs[k], w[k], acc);
        hs[t] = fmaxf(acc, 0.0f);
    }
    __syncthreads();
    {
        float acc = b2[t];
        const float* w = W2 + t * CH;
        for (int k = 0; k < CH; ++k) acc = fmaf(hs[k], w[k], acc);
        sc[t] = acc;                // logit; sort order == sigmoid order
    }
    __syncthreads();
    const float mysc = sc[t];
    int rank = 0;
    for (int j = 0; j < C; ++j) {
        float o = sc[j];
        // descending, stable: element j precedes t if o > mysc, or tie & j < t
        rank += (o > mysc) || (o == mysc && j < t);
    }
    perm[n * C + rank] = t;         // perm[n][pos] = source channel
}

// ---------------- kernel 3: plane gather/permute copy ----------------------
// TWO blocks per output plane (8192 blocks, 8 float4/thread): doubles the
// number of waves in flight so outstanding HBM reads cover the ~900-cycle
// miss latency (round-3 counters: 2.4 TB/s, nothing saturated => latency-
// bound). Traversal stays REVERSED (plane 4095 -> 0) so the first source
// reads hit the L3-resident tail left by the mean pass (measured: FETCH
// 133 MB for a 268 MB re-read). Non-temporal stores keep the 268 MB output
// stream from evicting x out of L3.
__global__ __launch_bounds__(256) void gather_kernel(const float* __restrict__ x,
                                                     const int* __restrict__ perm,
                                                     float* __restrict__ out) {
    const int bid = blockIdx.x;                  // 0..8191
    const int b = (PLANES - 1) - (bid >> 1);     // output plane 4095..0
    const int half = bid & 1;                    // which half-plane
    const int n = b >> 8;
    const int p = b & 255;
    const int src = perm[b];
    const vfloat4* sp = (const vfloat4*)(x + ((size_t)n * C + src) * HW
                                           + (size_t)half * (HW / 2));
    // selected planes first (NB*CH of them), then remaining planes
    const size_t dstPlane = (p < CH)
        ? ((size_t)n * CH + p)
        : ((size_t)NB * CH + (size_t)n * CH + (p - CH));
    vfloat4* dp = (vfloat4*)(out + dstPlane * HW + (size_t)half * (HW / 2));
    const int t = threadIdx.x;
#pragma unroll
    for (int i = 0; i < 8; ++i) {
        vfloat4 v = sp[t + i * 256];
        __builtin_nontemporal_store(v, dp + t + i * 256);
    }
}

extern "C" void kernel_launch(void* const* d_in, const int* in_sizes, int n_in,
                              void* d_out, int out_size, void* d_ws, size_t ws_size,
                              hipStream_t stream) {
    const float* x  = (const float*)d_in[0];
    const float* W1 = (const float*)d_in[1];
    const float* b1 = (const float*)d_in[2];
    const float* W2 = (const float*)d_in[3];
    const float* b2 = (const float*)d_in[4];
    float* out = (float*)d_out;

    float* z   = (float*)d_ws;                                 // 4096 floats
    int*  perm = (int*)((char*)d_ws + PLANES * sizeof(float)); // 4096 ints

    mean_kernel<<<PLANES, 256, 0, stream>>>(x, z);
    mlp_sort_kernel<<<NB, 256, 0, stream>>>(z, W1, b1, W2, b2, perm);
    gather_kernel<<<PLANES * 2, 256, 0, stream>>>(x, perm, out);
}